// Round 1
// baseline (243.898 us; speedup 1.0000x reference)
//
#include <hip/hip_runtime.h>

#define HH 2048
#define WW 2048
#define NN (HH*WW)

static constexpr unsigned RANK0 = 1677721u;   // floor(0.4*(NN-1))
static constexpr unsigned KEYLO = 0xB000u;
static constexpr unsigned KEYHI_ = 0xC000u;
static constexpr int NBINS = 4096;
static constexpr int NPART = 512;

struct Scal {
  unsigned keyhiA, keyhiB, rA, rB;
  double thr, c0, c1;
};

static constexpr size_t OFF_CTL    = (size_t)NN * 4;          // after bufA
static constexpr size_t OFF_COARSE = OFF_CTL;
static constexpr size_t OFF_UNDER  = OFF_CTL + (size_t)NBINS * 4;
static constexpr size_t OFF_OVER   = OFF_UNDER + 4;
static constexpr size_t OFF_SCAL   = OFF_OVER + 4;            // 8-aligned
static constexpr size_t OFF_PART   = OFF_SCAL + 48;
static constexpr size_t OFF_FINEA  = OFF_PART + (size_t)NPART * 3 * 8;
static constexpr size_t OFF_FINEB  = OFF_FINEA + 65536ull * 4;
static constexpr size_t WS_NEED    = OFF_FINEB + 65536ull * 4;
static constexpr size_t CTL_BYTES  = WS_NEED - OFF_CTL;

__device__ __forceinline__ float mx3(float a, float b, float c){ return fmaxf(fmaxf(a,b),c); }
__device__ __forceinline__ float mn3(float a, float b, float c){ return fminf(fminf(a,b),c); }

__device__ __forceinline__ unsigned keyf(float x){
  unsigned b = __float_as_uint(x);
  return (b & 0x80000000u) ? ~b : (b | 0x80000000u);
}
__device__ __forceinline__ float keyinv(unsigned k){
  unsigned b = (k & 0x80000000u) ? (k ^ 0x80000000u) : ~k;
  return __uint_as_float(b);
}

// load cols q-1..q+4 of `row` with zero padding (rows and cols)
__device__ __forceinline__ void load6(const float* __restrict__ p, int row, int q, float r[6]){
  if (row < 0 || row >= HH){
    r[0]=r[1]=r[2]=r[3]=r[4]=r[5]=0.f;
    return;
  }
  const float* rp = p + (size_t)row * WW;
  float4 cc = *reinterpret_cast<const float4*>(rp + q);
  r[0] = (q > 0) ? rp[q-1] : 0.f;
  r[1]=cc.x; r[2]=cc.y; r[3]=cc.z; r[4]=cc.w;
  r[5] = (q+4 < WW) ? rp[q+4] : 0.f;
}

// One morphological op.  DIL: out = max(M9, 1 + min_f A_f);  else out = min(m9, max_f B_f - 1).
// HIST: also build coarse histogram of outputs (4096 bins of key>>16 in [KEYLO,KEYHI_)).
template<bool DIL, bool HIST>
__global__ __launch_bounds__(256)
void morph_k(const float* __restrict__ in, float* __restrict__ out,
             unsigned* __restrict__ gh, unsigned* __restrict__ under, unsigned* __restrict__ over){
  __shared__ unsigned lh[HIST ? NBINS : 1];
  if (HIST){
    for (int i = threadIdx.x; i < NBINS; i += blockDim.x) lh[i] = 0;
    __syncthreads();
  }
  const int nItems = NN/4;
  for (int it = blockIdx.x*blockDim.x + threadIdx.x; it < nItems; it += gridDim.x*blockDim.x){
    int i = it >> 9;            // W/4 = 512 groups per row
    int q = (it & 511) << 2;
    float a[6], b[6], c[6];
    load6(in, i-1, q, a);
    load6(in, i,   q, b);
    load6(in, i+1, q, c);
    float res[4];
    #pragma unroll
    for (int t = 0; t < 4; t++){
      if (DIL){
        float Ah = mx3(b[t],   b[t+1], b[t+2]);
        float Av = mx3(a[t+1], b[t+1], c[t+1]);
        float Ad = mx3(a[t],   b[t+1], c[t+2]);
        float Aa = mx3(a[t+2], b[t+1], c[t]);
        float M9 = mx3(mx3(a[t],a[t+1],a[t+2]), Ah, mx3(c[t],c[t+1],c[t+2]));
        res[t] = fmaxf(M9, 1.0f + fminf(fminf(Ah,Av), fminf(Ad,Aa)));
      } else {
        float Bh = mn3(b[t],   b[t+1], b[t+2]);
        float Bv = mn3(a[t+1], b[t+1], c[t+1]);
        float Bd = mn3(a[t],   b[t+1], c[t+2]);
        float Ba = mn3(a[t+2], b[t+1], c[t]);
        float m9 = mn3(mn3(a[t],a[t+1],a[t+2]), Bh, mn3(c[t],c[t+1],c[t+2]));
        res[t] = fminf(m9, fmaxf(fmaxf(Bh,Bv), fmaxf(Bd,Ba)) - 1.0f);
      }
      if (HIST){
        unsigned key = keyf(res[t]);
        unsigned hi = key >> 16;
        if (hi >= KEYLO && hi < KEYHI_) atomicAdd(&lh[hi - KEYLO], 1u);
        else if (hi < KEYLO)            atomicAdd(under, 1u);
        else                            atomicAdd(over, 1u);
      }
    }
    *reinterpret_cast<float4*>(out + (size_t)i*WW + q) = make_float4(res[0],res[1],res[2],res[3]);
  }
  if (HIST){
    __syncthreads();
    for (int i = threadIdx.x; i < NBINS; i += blockDim.x){
      unsigned cc = lh[i];
      if (cc) atomicAdd(&gh[i], cc);
    }
  }
}

__global__ void scan_coarse_k(const unsigned* __restrict__ gh, const unsigned* __restrict__ under,
                              Scal* __restrict__ sc){
  __shared__ unsigned part[256];
  __shared__ unsigned excl[256];
  int t = threadIdx.x;
  unsigned loc = 0;
  #pragma unroll
  for (int i = 0; i < NBINS/256; i++) loc += gh[t*(NBINS/256) + i];
  part[t] = loc;
  __syncthreads();
  if (t == 0){
    unsigned run = under[0];
    for (int i = 0; i < 256; i++){ excl[i] = run; run += part[i]; }
  }
  __syncthreads();
  unsigned run = excl[t];
  const unsigned r0 = RANK0, r1 = RANK0 + 1;
  #pragma unroll
  for (int i = 0; i < NBINS/256; i++){
    unsigned idx = t*(NBINS/256) + i;
    unsigned cc = gh[idx];
    if (cc){
      if (r0 >= run && r0 - run < cc){ sc->keyhiA = KEYLO + idx; sc->rA = r0 - run; }
      if (r1 >= run && r1 - run < cc){ sc->keyhiB = KEYLO + idx; sc->rB = r1 - run; }
    }
    run += cc;
  }
}

__global__ __launch_bounds__(256)
void fine_k(const float* __restrict__ x, const Scal* __restrict__ sc,
            unsigned* __restrict__ fa, unsigned* __restrict__ fb){
  unsigned ha = sc->keyhiA, hb = sc->keyhiB;
  bool dup = (ha == hb);
  const int nItems = NN/4;
  for (int it = blockIdx.x*blockDim.x + threadIdx.x; it < nItems; it += gridDim.x*blockDim.x){
    float4 v = reinterpret_cast<const float4*>(x)[it];
    float vv[4] = {v.x, v.y, v.z, v.w};
    #pragma unroll
    for (int t = 0; t < 4; t++){
      unsigned key = keyf(vv[t]);
      unsigned hi = key >> 16;
      if (hi == ha) atomicAdd(&fa[key & 0xFFFFu], 1u);
      if (!dup && hi == hb) atomicAdd(&fb[key & 0xFFFFu], 1u);
    }
  }
}

__global__ void scan_fine_k(const unsigned* __restrict__ fa, const unsigned* __restrict__ fb,
                            Scal* __restrict__ sc){
  __shared__ unsigned part[256];
  __shared__ unsigned excl[256];
  __shared__ unsigned kfound[2];
  int t = threadIdx.x;
  unsigned ha = sc->keyhiA, hb = sc->keyhiB;
  for (int pass = 0; pass < 2; pass++){
    const unsigned* h = (pass == 0) ? fa : ((hb == ha) ? fa : fb);
    unsigned rr = (pass == 0) ? sc->rA : sc->rB;
    unsigned loc = 0;
    #pragma unroll 8
    for (int i = 0; i < 256; i++) loc += h[t*256 + i];
    part[t] = loc;
    __syncthreads();
    if (t == 0){
      unsigned run = 0;
      for (int i = 0; i < 256; i++){ excl[i] = run; run += part[i]; }
    }
    __syncthreads();
    unsigned run = excl[t];
    #pragma unroll 8
    for (int i = 0; i < 256; i++){
      unsigned idx = t*256 + i;
      unsigned cc = h[idx];
      if (cc && rr >= run && rr - run < cc) kfound[pass] = idx;
      run += cc;
    }
    __syncthreads();
  }
  if (t == 0){
    unsigned ka = (sc->keyhiA << 16) | kfound[0];
    unsigned kb = (sc->keyhiB << 16) | kfound[1];
    double va = (double)keyinv(ka), vb = (double)keyinv(kb);
    const double FRAC = 0.4*(double)(NN-1) - (double)RANK0;   // = np's gamma
    sc->thr = va + (vb - va) * FRAC;
  }
}

// balloon step: aux = 1 + M9(x) computed inline; xb = (origin > thr) ? aux : x.
// Also f64 partial sums of origin, xb, origin*xb per block.
__global__ __launch_bounds__(256)
void balloon_k(const float* __restrict__ x, const float* __restrict__ orig,
               float* __restrict__ xb, const Scal* __restrict__ sc, double* __restrict__ part){
  double thr = sc->thr;
  double s0 = 0.0, s1 = 0.0, s2 = 0.0;   // So, Sx, Sox
  const int nItems = NN/4;
  for (int it = blockIdx.x*blockDim.x + threadIdx.x; it < nItems; it += gridDim.x*blockDim.x){
    int i = it >> 9;
    int q = (it & 511) << 2;
    float a[6], b[6], c[6];
    load6(x, i-1, q, a);
    load6(x, i,   q, b);
    load6(x, i+1, q, c);
    float4 og = *reinterpret_cast<const float4*>(orig + (size_t)i*WW + q);
    float ov[4] = {og.x, og.y, og.z, og.w};
    float r[4];
    #pragma unroll
    for (int t = 0; t < 4; t++){
      float M9 = mx3(mx3(a[t],a[t+1],a[t+2]), mx3(b[t],b[t+1],b[t+2]), mx3(c[t],c[t+1],c[t+2]));
      float aux = 1.0f + M9;
      float nx = ((double)ov[t] > thr) ? aux : b[t+1];
      r[t] = nx;
      s0 += (double)ov[t];
      s1 += (double)nx;
      s2 += (double)ov[t] * (double)nx;
    }
    *reinterpret_cast<float4*>(xb + (size_t)i*WW + q) = make_float4(r[0],r[1],r[2],r[3]);
  }
  for (int off = 32; off > 0; off >>= 1){
    s0 += __shfl_down(s0, off);
    s1 += __shfl_down(s1, off);
    s2 += __shfl_down(s2, off);
  }
  __shared__ double red[4][3];
  int lane = threadIdx.x & 63, wv = threadIdx.x >> 6;
  if (lane == 0){ red[wv][0] = s0; red[wv][1] = s1; red[wv][2] = s2; }
  __syncthreads();
  if (threadIdx.x == 0){
    part[blockIdx.x*3+0] = red[0][0]+red[1][0]+red[2][0]+red[3][0];
    part[blockIdx.x*3+1] = red[0][1]+red[1][1]+red[2][1]+red[3][1];
    part[blockIdx.x*3+2] = red[0][2]+red[1][2]+red[2][2]+red[3][2];
  }
}

__global__ void c0c1_k(const double* __restrict__ part, Scal* __restrict__ sc){
  int t = threadIdx.x;
  double s0 = 0, s1 = 0, s2 = 0;
  for (int b = t; b < NPART; b += 256){
    s0 += part[b*3+0]; s1 += part[b*3+1]; s2 += part[b*3+2];
  }
  for (int off = 32; off > 0; off >>= 1){
    s0 += __shfl_down(s0, off);
    s1 += __shfl_down(s1, off);
    s2 += __shfl_down(s2, off);
  }
  __shared__ double red[4][3];
  int lane = t & 63, wv = t >> 6;
  if (lane == 0){ red[wv][0] = s0; red[wv][1] = s1; red[wv][2] = s2; }
  __syncthreads();
  if (t == 0){
    double So = red[0][0]+red[1][0]+red[2][0]+red[3][0];
    double Sx = red[0][1]+red[1][1]+red[2][1]+red[3][1];
    double Sox= red[0][2]+red[1][2]+red[2][2]+red[3][2];
    sc->c0 = (So - Sox) / ((double)NN - Sx + 1e-8);
    sc->c1 = Sox / (Sx + 1e-8);
  }
}

__global__ __launch_bounds__(256)
void final_k(const float* __restrict__ orig, const float* __restrict__ xb,
             const Scal* __restrict__ sc, float* __restrict__ out){
  double c0 = sc->c0, c1 = sc->c1;
  const int nItems = NN/4;
  for (int it = blockIdx.x*blockDim.x + threadIdx.x; it < nItems; it += gridDim.x*blockDim.x){
    float4 og = reinterpret_cast<const float4*>(orig)[it];
    float4 xv = reinterpret_cast<const float4*>(xb)[it];
    float ov[4] = {og.x, og.y, og.z, og.w};
    float xx[4] = {xv.x, xv.y, xv.z, xv.w};
    float r[4];
    #pragma unroll
    for (int t = 0; t < 4; t++){
      double o = (double)ov[t];
      double d1 = o - c1, d0 = o - c0;
      double cv = d1*d1 - d0*d0;
      r[t] = (cv < 0.0) ? 1.0f : ((cv > 0.0) ? 0.0f : xx[t]);
    }
    reinterpret_cast<float4*>(out)[it] = make_float4(r[0],r[1],r[2],r[3]);
  }
}

extern "C" void kernel_launch(void* const* d_in, const int* in_sizes, int n_in,
                              void* d_out, int out_size, void* d_ws, size_t ws_size,
                              hipStream_t stream) {
  const float* input  = (const float*)d_in[0];
  const float* origin = (const float*)d_in[1];
  float* out = (float*)d_out;

  char* ws = (char*)d_ws;
  float*    bufA   = (float*)ws;
  unsigned* coarse = (unsigned*)(ws + OFF_COARSE);
  unsigned* under  = (unsigned*)(ws + OFF_UNDER);
  unsigned* over   = (unsigned*)(ws + OFF_OVER);
  Scal*     scal   = (Scal*)(ws + OFF_SCAL);
  double*   part   = (double*)(ws + OFF_PART);
  unsigned* fineA  = (unsigned*)(ws + OFF_FINEA);
  unsigned* fineB  = (unsigned*)(ws + OFF_FINEB);

  hipMemsetAsync(ws + OFF_CTL, 0, CTL_BYTES, stream);

  // smoothing: D, E, E, D, D, E  (ping-pong input -> bufA -> out -> ... -> out)
  morph_k<true,  false><<<4096, 256, 0, stream>>>(input, bufA, nullptr, nullptr, nullptr);
  morph_k<false, false><<<4096, 256, 0, stream>>>(bufA, out,  nullptr, nullptr, nullptr);
  morph_k<false, false><<<4096, 256, 0, stream>>>(out,  bufA, nullptr, nullptr, nullptr);
  morph_k<true,  false><<<4096, 256, 0, stream>>>(bufA, out,  nullptr, nullptr, nullptr);
  morph_k<true,  false><<<4096, 256, 0, stream>>>(out,  bufA, nullptr, nullptr, nullptr);
  morph_k<false, true ><<<512,  256, 0, stream>>>(bufA, out,  coarse, under, over);  // x_final in d_out

  scan_coarse_k<<<1, 256, 0, stream>>>(coarse, under, scal);
  fine_k<<<2048, 256, 0, stream>>>(out, scal, fineA, fineB);
  scan_fine_k<<<1, 256, 0, stream>>>(fineA, fineB, scal);

  balloon_k<<<NPART, 256, 0, stream>>>(out, origin, bufA, scal, part);   // xb in bufA
  c0c1_k<<<1, 256, 0, stream>>>(part, scal);
  final_k<<<2048, 256, 0, stream>>>(origin, bufA, scal, out);
}

// Round 2
// 187.032 us; speedup vs baseline: 1.3040x; 1.3040x over previous
//
#include <hip/hip_runtime.h>

#define HH 2048
#define WW 2048
#define NN (HH*WW)

static constexpr unsigned RANK0 = 1677721u;   // floor(0.4*(NN-1))
static constexpr unsigned KEYLO = 0xB000u;
static constexpr unsigned KEYHI_ = 0xC000u;
static constexpr int NBINS = 4096;
static constexpr int NPART = 512;

struct Scal {
  unsigned keyhiA, keyhiB, rA, rB;      // coarse result: hi16 bins + ranks within
  unsigned midA_, midB_, rA2, rB2;      // mid-byte bins + ranks within
  double thr, c0, c1;
};

static constexpr size_t OFF_CTL    = (size_t)NN * 4;          // after bufA
static constexpr size_t OFF_COARSE = OFF_CTL;
static constexpr size_t OFF_UNDER  = OFF_CTL + (size_t)NBINS * 4;
static constexpr size_t OFF_OVER   = OFF_UNDER + 4;
static constexpr size_t OFF_SCAL   = OFF_OVER + 4;            // 8-aligned (16392 % 8 == 0)
static constexpr size_t OFF_PART   = OFF_SCAL + 64;
static constexpr size_t OFF_MIDA   = OFF_PART + (size_t)NPART * 3 * 8;
static constexpr size_t OFF_MIDB   = OFF_MIDA + 1024;
static constexpr size_t OFF_LOWA   = OFF_MIDB + 1024;
static constexpr size_t OFF_LOWB   = OFF_LOWA + 1024;
static constexpr size_t WS_NEED    = OFF_LOWB + 1024;
static constexpr size_t CTL_BYTES  = WS_NEED - OFF_CTL;

__device__ __forceinline__ float mx3(float a, float b, float c){ return fmaxf(fmaxf(a,b),c); }
__device__ __forceinline__ float mn3(float a, float b, float c){ return fminf(fminf(a,b),c); }

__device__ __forceinline__ unsigned keyf(float x){
  unsigned b = __float_as_uint(x);
  return (b & 0x80000000u) ? ~b : (b | 0x80000000u);
}
__device__ __forceinline__ float keyinv(unsigned k){
  unsigned b = (k & 0x80000000u) ? (k ^ 0x80000000u) : ~k;
  return __uint_as_float(b);
}

// load cols q-1..q+4 of `row` with zero padding (rows and cols)
__device__ __forceinline__ void load6(const float* __restrict__ p, int row, int q, float r[6]){
  if (row < 0 || row >= HH){
    r[0]=r[1]=r[2]=r[3]=r[4]=r[5]=0.f;
    return;
  }
  const float* rp = p + (size_t)row * WW;
  float4 cc = *reinterpret_cast<const float4*>(rp + q);
  r[0] = (q > 0) ? rp[q-1] : 0.f;
  r[1]=cc.x; r[2]=cc.y; r[3]=cc.z; r[4]=cc.w;
  r[5] = (q+4 < WW) ? rp[q+4] : 0.f;
}

// One morphological op.  DIL: out = max(M9, 1 + min_f A_f);  else out = min(m9, max_f B_f - 1).
// HIST: also build coarse histogram of outputs (4096 bins of key>>16 in [KEYLO,KEYHI_)).
template<bool DIL, bool HIST>
__global__ __launch_bounds__(256)
void morph_k(const float* __restrict__ in, float* __restrict__ out,
             unsigned* __restrict__ gh, unsigned* __restrict__ under, unsigned* __restrict__ over){
  __shared__ unsigned lh[HIST ? NBINS : 1];
  if (HIST){
    for (int i = threadIdx.x; i < NBINS; i += blockDim.x) lh[i] = 0;
    __syncthreads();
  }
  const int nItems = NN/4;
  for (int it = blockIdx.x*blockDim.x + threadIdx.x; it < nItems; it += gridDim.x*blockDim.x){
    int i = it >> 9;            // W/4 = 512 groups per row
    int q = (it & 511) << 2;
    float a[6], b[6], c[6];
    load6(in, i-1, q, a);
    load6(in, i,   q, b);
    load6(in, i+1, q, c);
    float res[4];
    #pragma unroll
    for (int t = 0; t < 4; t++){
      if (DIL){
        float Ah = mx3(b[t],   b[t+1], b[t+2]);
        float Av = mx3(a[t+1], b[t+1], c[t+1]);
        float Ad = mx3(a[t],   b[t+1], c[t+2]);
        float Aa = mx3(a[t+2], b[t+1], c[t]);
        float M9 = mx3(mx3(a[t],a[t+1],a[t+2]), Ah, mx3(c[t],c[t+1],c[t+2]));
        res[t] = fmaxf(M9, 1.0f + fminf(fminf(Ah,Av), fminf(Ad,Aa)));
      } else {
        float Bh = mn3(b[t],   b[t+1], b[t+2]);
        float Bv = mn3(a[t+1], b[t+1], c[t+1]);
        float Bd = mn3(a[t],   b[t+1], c[t+2]);
        float Ba = mn3(a[t+2], b[t+1], c[t]);
        float m9 = mn3(mn3(a[t],a[t+1],a[t+2]), Bh, mn3(c[t],c[t+1],c[t+2]));
        res[t] = fminf(m9, fmaxf(fmaxf(Bh,Bv), fmaxf(Bd,Ba)) - 1.0f);
      }
      if (HIST){
        unsigned key = keyf(res[t]);
        unsigned hi = key >> 16;
        if (hi >= KEYLO && hi < KEYHI_) atomicAdd(&lh[hi - KEYLO], 1u);
        else if (hi < KEYLO)            atomicAdd(under, 1u);
        else                            atomicAdd(over, 1u);
      }
    }
    *reinterpret_cast<float4*>(out + (size_t)i*WW + q) = make_float4(res[0],res[1],res[2],res[3]);
  }
  if (HIST){
    __syncthreads();
    for (int i = threadIdx.x; i < NBINS; i += blockDim.x){
      unsigned cc = lh[i];
      if (cc) atomicAdd(&gh[i], cc);
    }
  }
}

__global__ void scan_coarse_k(const unsigned* __restrict__ gh, const unsigned* __restrict__ under,
                              Scal* __restrict__ sc){
  __shared__ unsigned part[256];
  __shared__ unsigned excl[256];
  int t = threadIdx.x;
  unsigned loc = 0;
  #pragma unroll
  for (int i = 0; i < NBINS/256; i++) loc += gh[t*(NBINS/256) + i];
  part[t] = loc;
  __syncthreads();
  if (t == 0){
    unsigned run = under[0];
    for (int i = 0; i < 256; i++){ excl[i] = run; run += part[i]; }
  }
  __syncthreads();
  unsigned run = excl[t];
  const unsigned r0 = RANK0, r1 = RANK0 + 1;
  #pragma unroll
  for (int i = 0; i < NBINS/256; i++){
    unsigned idx = t*(NBINS/256) + i;
    unsigned cc = gh[idx];
    if (cc){
      if (r0 >= run && r0 - run < cc){ sc->keyhiA = KEYLO + idx; sc->rA = r0 - run; }
      if (r1 >= run && r1 - run < cc){ sc->keyhiB = KEYLO + idx; sc->rB = r1 - run; }
    }
    run += cc;
  }
}

// mid-byte histogram (bits 15..8) of keys whose hi16 matches keyhiA / keyhiB
__global__ __launch_bounds__(256)
void fine_mid_k(const float* __restrict__ x, const Scal* __restrict__ sc,
                unsigned* __restrict__ midA, unsigned* __restrict__ midB){
  __shared__ unsigned hA[256], hB[256];
  hA[threadIdx.x] = 0; hB[threadIdx.x] = 0;
  __syncthreads();
  unsigned ha = sc->keyhiA, hb = sc->keyhiB;
  bool dup = (ha == hb);
  const int nItems = NN/4;
  for (int it = blockIdx.x*blockDim.x + threadIdx.x; it < nItems; it += gridDim.x*blockDim.x){
    float4 v = reinterpret_cast<const float4*>(x)[it];
    float vv[4] = {v.x, v.y, v.z, v.w};
    #pragma unroll
    for (int t = 0; t < 4; t++){
      unsigned key = keyf(vv[t]);
      unsigned hi = key >> 16;
      if (hi == ha)      atomicAdd(&hA[(key >> 8) & 0xFFu], 1u);
      else if (hi == hb) atomicAdd(&hB[(key >> 8) & 0xFFu], 1u);
    }
  }
  __syncthreads();
  unsigned ca = hA[threadIdx.x];
  if (ca) atomicAdd(&midA[threadIdx.x], ca);
  if (!dup){
    unsigned cb = hB[threadIdx.x];
    if (cb) atomicAdd(&midB[threadIdx.x], cb);
  }
}

__global__ void scan_mid_k(const unsigned* __restrict__ midA, const unsigned* __restrict__ midB,
                           Scal* __restrict__ sc){
  __shared__ unsigned h[256], excl[256];
  int t = threadIdx.x;
  bool dup = (sc->keyhiA == sc->keyhiB);
  unsigned rA = sc->rA, rB = sc->rB;
  h[t] = midA[t];
  __syncthreads();
  if (t == 0){ unsigned run = 0; for (int i = 0; i < 256; i++){ excl[i] = run; run += h[i]; } }
  __syncthreads();
  if (rA >= excl[t] && rA - excl[t] < h[t]){ sc->midA_ = (unsigned)t; sc->rA2 = rA - excl[t]; }
  if (dup && rB >= excl[t] && rB - excl[t] < h[t]){ sc->midB_ = (unsigned)t; sc->rB2 = rB - excl[t]; }
  if (!dup){
    __syncthreads();
    h[t] = midB[t];
    __syncthreads();
    if (t == 0){ unsigned run = 0; for (int i = 0; i < 256; i++){ excl[i] = run; run += h[i]; } }
    __syncthreads();
    if (rB >= excl[t] && rB - excl[t] < h[t]){ sc->midB_ = (unsigned)t; sc->rB2 = rB - excl[t]; }
  }
}

// low-byte histogram of keys with hi16 AND mid byte matching
__global__ __launch_bounds__(256)
void fine_low_k(const float* __restrict__ x, const Scal* __restrict__ sc,
                unsigned* __restrict__ lowA, unsigned* __restrict__ lowB){
  __shared__ unsigned hA[256], hB[256];
  hA[threadIdx.x] = 0; hB[threadIdx.x] = 0;
  __syncthreads();
  unsigned ha = sc->keyhiA, hb = sc->keyhiB;
  unsigned ma = sc->midA_, mb = sc->midB_;
  bool dup = (ha == hb) && (ma == mb);
  const int nItems = NN/4;
  for (int it = blockIdx.x*blockDim.x + threadIdx.x; it < nItems; it += gridDim.x*blockDim.x){
    float4 v = reinterpret_cast<const float4*>(x)[it];
    float vv[4] = {v.x, v.y, v.z, v.w};
    #pragma unroll
    for (int t = 0; t < 4; t++){
      unsigned key = keyf(vv[t]);
      unsigned hi = key >> 16;
      unsigned m  = (key >> 8) & 0xFFu;
      if (hi == ha && m == ma)      atomicAdd(&hA[key & 0xFFu], 1u);
      else if (hi == hb && m == mb) atomicAdd(&hB[key & 0xFFu], 1u);
    }
  }
  __syncthreads();
  unsigned ca = hA[threadIdx.x];
  if (ca) atomicAdd(&lowA[threadIdx.x], ca);
  if (!dup){
    unsigned cb = hB[threadIdx.x];
    if (cb) atomicAdd(&lowB[threadIdx.x], cb);
  }
}

__global__ void scan_low_k(const unsigned* __restrict__ lowA, const unsigned* __restrict__ lowB,
                           Scal* __restrict__ sc){
  __shared__ unsigned h[256], excl[256];
  __shared__ unsigned kfound[2];
  int t = threadIdx.x;
  bool dup = (sc->keyhiA == sc->keyhiB) && (sc->midA_ == sc->midB_);
  unsigned rA2 = sc->rA2, rB2 = sc->rB2;
  h[t] = lowA[t];
  __syncthreads();
  if (t == 0){ unsigned run = 0; for (int i = 0; i < 256; i++){ excl[i] = run; run += h[i]; } }
  __syncthreads();
  if (rA2 >= excl[t] && rA2 - excl[t] < h[t]) kfound[0] = (unsigned)t;
  if (dup && rB2 >= excl[t] && rB2 - excl[t] < h[t]) kfound[1] = (unsigned)t;
  if (!dup){
    __syncthreads();
    h[t] = lowB[t];
    __syncthreads();
    if (t == 0){ unsigned run = 0; for (int i = 0; i < 256; i++){ excl[i] = run; run += h[i]; } }
    __syncthreads();
    if (rB2 >= excl[t] && rB2 - excl[t] < h[t]) kfound[1] = (unsigned)t;
  }
  __syncthreads();
  if (t == 0){
    unsigned ka = (sc->keyhiA << 16) | (sc->midA_ << 8) | kfound[0];
    unsigned kb = (sc->keyhiB << 16) | (sc->midB_ << 8) | kfound[1];
    double va = (double)keyinv(ka), vb = (double)keyinv(kb);
    const double FRAC = 0.4*(double)(NN-1) - (double)RANK0;   // np's interpolation gamma
    sc->thr = va + (vb - va) * FRAC;
  }
}

// balloon step: aux = 1 + M9(x) computed inline; xb = (origin > thr) ? aux : x.
// Also f64 partial sums of origin, xb, origin*xb per block.
__global__ __launch_bounds__(256)
void balloon_k(const float* __restrict__ x, const float* __restrict__ orig,
               float* __restrict__ xb, const Scal* __restrict__ sc, double* __restrict__ part){
  double thr = sc->thr;
  double s0 = 0.0, s1 = 0.0, s2 = 0.0;   // So, Sx, Sox
  const int nItems = NN/4;
  for (int it = blockIdx.x*blockDim.x + threadIdx.x; it < nItems; it += gridDim.x*blockDim.x){
    int i = it >> 9;
    int q = (it & 511) << 2;
    float a[6], b[6], c[6];
    load6(x, i-1, q, a);
    load6(x, i,   q, b);
    load6(x, i+1, q, c);
    float4 og = *reinterpret_cast<const float4*>(orig + (size_t)i*WW + q);
    float ov[4] = {og.x, og.y, og.z, og.w};
    float r[4];
    #pragma unroll
    for (int t = 0; t < 4; t++){
      float M9 = mx3(mx3(a[t],a[t+1],a[t+2]), mx3(b[t],b[t+1],b[t+2]), mx3(c[t],c[t+1],c[t+2]));
      float aux = 1.0f + M9;
      float nx = ((double)ov[t] > thr) ? aux : b[t+1];
      r[t] = nx;
      s0 += (double)ov[t];
      s1 += (double)nx;
      s2 += (double)ov[t] * (double)nx;
    }
    *reinterpret_cast<float4*>(xb + (size_t)i*WW + q) = make_float4(r[0],r[1],r[2],r[3]);
  }
  for (int off = 32; off > 0; off >>= 1){
    s0 += __shfl_down(s0, off);
    s1 += __shfl_down(s1, off);
    s2 += __shfl_down(s2, off);
  }
  __shared__ double red[4][3];
  int lane = threadIdx.x & 63, wv = threadIdx.x >> 6;
  if (lane == 0){ red[wv][0] = s0; red[wv][1] = s1; red[wv][2] = s2; }
  __syncthreads();
  if (threadIdx.x == 0){
    part[blockIdx.x*3+0] = red[0][0]+red[1][0]+red[2][0]+red[3][0];
    part[blockIdx.x*3+1] = red[0][1]+red[1][1]+red[2][1]+red[3][1];
    part[blockIdx.x*3+2] = red[0][2]+red[1][2]+red[2][2]+red[3][2];
  }
}

__global__ void c0c1_k(const double* __restrict__ part, Scal* __restrict__ sc){
  int t = threadIdx.x;
  double s0 = 0, s1 = 0, s2 = 0;
  for (int b = t; b < NPART; b += 256){
    s0 += part[b*3+0]; s1 += part[b*3+1]; s2 += part[b*3+2];
  }
  for (int off = 32; off > 0; off >>= 1){
    s0 += __shfl_down(s0, off);
    s1 += __shfl_down(s1, off);
    s2 += __shfl_down(s2, off);
  }
  __shared__ double red[4][3];
  int lane = t & 63, wv = t >> 6;
  if (lane == 0){ red[wv][0] = s0; red[wv][1] = s1; red[wv][2] = s2; }
  __syncthreads();
  if (t == 0){
    double So = red[0][0]+red[1][0]+red[2][0]+red[3][0];
    double Sx = red[0][1]+red[1][1]+red[2][1]+red[3][1];
    double Sox= red[0][2]+red[1][2]+red[2][2]+red[3][2];
    sc->c0 = (So - Sox) / ((double)NN - Sx + 1e-8);
    sc->c1 = Sox / (Sx + 1e-8);
  }
}

__global__ __launch_bounds__(256)
void final_k(const float* __restrict__ orig, const float* __restrict__ xb,
             const Scal* __restrict__ sc, float* __restrict__ out){
  double c0 = sc->c0, c1 = sc->c1;
  const int nItems = NN/4;
  for (int it = blockIdx.x*blockDim.x + threadIdx.x; it < nItems; it += gridDim.x*blockDim.x){
    float4 og = reinterpret_cast<const float4*>(orig)[it];
    float4 xv = reinterpret_cast<const float4*>(xb)[it];
    float ov[4] = {og.x, og.y, og.z, og.w};
    float xx[4] = {xv.x, xv.y, xv.z, xv.w};
    float r[4];
    #pragma unroll
    for (int t = 0; t < 4; t++){
      double o = (double)ov[t];
      double d1 = o - c1, d0 = o - c0;
      double cv = d1*d1 - d0*d0;
      r[t] = (cv < 0.0) ? 1.0f : ((cv > 0.0) ? 0.0f : xx[t]);
    }
    reinterpret_cast<float4*>(out)[it] = make_float4(r[0],r[1],r[2],r[3]);
  }
}

extern "C" void kernel_launch(void* const* d_in, const int* in_sizes, int n_in,
                              void* d_out, int out_size, void* d_ws, size_t ws_size,
                              hipStream_t stream) {
  const float* input  = (const float*)d_in[0];
  const float* origin = (const float*)d_in[1];
  float* out = (float*)d_out;

  char* ws = (char*)d_ws;
  float*    bufA   = (float*)ws;
  unsigned* coarse = (unsigned*)(ws + OFF_COARSE);
  unsigned* under  = (unsigned*)(ws + OFF_UNDER);
  unsigned* over   = (unsigned*)(ws + OFF_OVER);
  Scal*     scal   = (Scal*)(ws + OFF_SCAL);
  double*   part   = (double*)(ws + OFF_PART);
  unsigned* midA   = (unsigned*)(ws + OFF_MIDA);
  unsigned* midB   = (unsigned*)(ws + OFF_MIDB);
  unsigned* lowA   = (unsigned*)(ws + OFF_LOWA);
  unsigned* lowB   = (unsigned*)(ws + OFF_LOWB);

  hipMemsetAsync(ws + OFF_CTL, 0, CTL_BYTES, stream);

  // smoothing: D, E, E, D, D, E  (ping-pong input -> bufA -> out -> ... -> out)
  morph_k<true,  false><<<4096, 256, 0, stream>>>(input, bufA, nullptr, nullptr, nullptr);
  morph_k<false, false><<<4096, 256, 0, stream>>>(bufA, out,  nullptr, nullptr, nullptr);
  morph_k<false, false><<<4096, 256, 0, stream>>>(out,  bufA, nullptr, nullptr, nullptr);
  morph_k<true,  false><<<4096, 256, 0, stream>>>(bufA, out,  nullptr, nullptr, nullptr);
  morph_k<true,  false><<<4096, 256, 0, stream>>>(out,  bufA, nullptr, nullptr, nullptr);
  morph_k<false, true ><<<512,  256, 0, stream>>>(bufA, out,  coarse, under, over);  // x_final in d_out

  scan_coarse_k<<<1, 256, 0, stream>>>(coarse, under, scal);
  fine_mid_k<<<1024, 256, 0, stream>>>(out, scal, midA, midB);
  scan_mid_k<<<1, 256, 0, stream>>>(midA, midB, scal);
  fine_low_k<<<1024, 256, 0, stream>>>(out, scal, lowA, lowB);
  scan_low_k<<<1, 256, 0, stream>>>(lowA, lowB, scal);

  balloon_k<<<NPART, 256, 0, stream>>>(out, origin, bufA, scal, part);   // xb in bufA
  c0c1_k<<<1, 256, 0, stream>>>(part, scal);
  final_k<<<2048, 256, 0, stream>>>(origin, bufA, scal, out);
}

// Round 3
// 131.178 us; speedup vs baseline: 1.8593x; 1.4258x over previous
//
#include <hip/hip_runtime.h>

#define HH 2048
#define WW 2048
#define NN (HH*WW)

static constexpr unsigned RANK0 = 1677721u;   // floor(0.4*(NN-1))
static constexpr unsigned KEYLO = 0xB000u;
static constexpr unsigned KEYHI_ = 0xC000u;
static constexpr int NBINS = 4096;
static constexpr int NPART = 512;

// fused morph tile geometry
#define TH 32
#define TW 128
#define LR 44            // TH + 12 rows (halo 6 each side)
#define LCP 148          // padded LDS row stride in floats (data cols [0,144))

struct Scal {
  unsigned keyhiA, keyhiB, rA, rB;      // coarse result: hi16 bins + ranks within
  unsigned midA_, midB_, rA2, rB2;      // mid-byte bins + ranks within
  double thr, c0, c1;
};

static constexpr size_t OFF_CTL    = (size_t)NN * 4;          // after bufA
static constexpr size_t OFF_COARSE = OFF_CTL;
static constexpr size_t OFF_UNDER  = OFF_CTL + (size_t)NBINS * 4;
static constexpr size_t OFF_OVER   = OFF_UNDER + 4;
static constexpr size_t OFF_SCAL   = OFF_OVER + 4;            // 8-aligned (16392 % 8 == 0)
static constexpr size_t OFF_PART   = OFF_SCAL + 64;
static constexpr size_t OFF_MIDA   = OFF_PART + (size_t)NPART * 3 * 8;
static constexpr size_t OFF_MIDB   = OFF_MIDA + 1024;
static constexpr size_t OFF_LOWA   = OFF_MIDB + 1024;
static constexpr size_t OFF_LOWB   = OFF_LOWA + 1024;
static constexpr size_t WS_NEED    = OFF_LOWB + 1024;
static constexpr size_t CTL_BYTES  = WS_NEED - OFF_CTL;

__device__ __forceinline__ float mx3(float a, float b, float c){ return fmaxf(fmaxf(a,b),c); }
__device__ __forceinline__ float mn3(float a, float b, float c){ return fminf(fminf(a,b),c); }

__device__ __forceinline__ unsigned keyf(float x){
  unsigned b = __float_as_uint(x);
  return (b & 0x80000000u) ? ~b : (b | 0x80000000u);
}
__device__ __forceinline__ float keyinv(unsigned k){
  unsigned b = (k & 0x80000000u) ? (k ^ 0x80000000u) : ~k;
  return __uint_as_float(b);
}

// read one LDS row window for col-group g: aligned float4 + left/right neighbors.
// Neighbors come from adjacent lanes' registers via shuffle; wave-boundary and
// tile-edge lanes patch with an explicit (clamped) LDS read. Clamp garbage only
// touches cols 0 / 143 which are outside the pristine ring at every stage.
__device__ __forceinline__ void loadrow(const float* __restrict__ src, int lr, int g, int lane,
                                        float4& v, float& L, float& R){
  v = *reinterpret_cast<const float4*>(&src[lr*LCP + 4*g]);
  L = __shfl_up(v.w, 1);
  R = __shfl_down(v.x, 1);
  if (lane == 0 || g == 0)   L = src[lr*LCP + (g ? 4*g - 1 : 0)];
  if (lane == 63 || g == 35) R = src[lr*LCP + ((g == 35) ? 143 : 4*g + 4)];
}

__device__ __forceinline__ void morph4(bool DIL,
    const float pr[6], const float cr[6], const float nr[6], float w[4]){
  #pragma unroll
  for (int i = 0; i < 4; i++){
    if (DIL){
      float Ah = mx3(cr[i],   cr[i+1], cr[i+2]);
      float Av = mx3(pr[i+1], cr[i+1], nr[i+1]);
      float Ad = mx3(pr[i],   cr[i+1], nr[i+2]);
      float Aa = mx3(pr[i+2], cr[i+1], nr[i]);
      float tm = mx3(pr[i], pr[i+1], pr[i+2]);
      float bm = mx3(nr[i], nr[i+1], nr[i+2]);
      float M9 = mx3(tm, Ah, bm);
      w[i] = fmaxf(M9, 1.0f + fminf(fminf(Ah,Av), fminf(Ad,Aa)));
    } else {
      float Bh = mn3(cr[i],   cr[i+1], cr[i+2]);
      float Bv = mn3(pr[i+1], cr[i+1], nr[i+1]);
      float Bd = mn3(pr[i],   cr[i+1], nr[i+2]);
      float Ba = mn3(pr[i+2], cr[i+1], nr[i]);
      float tm = mn3(pr[i], pr[i+1], pr[i+2]);
      float bm = mn3(nr[i], nr[i+1], nr[i+2]);
      float m9 = mn3(tm, Bh, bm);
      w[i] = fminf(m9, fmaxf(fmaxf(Bh,Bv), fmaxf(Bd,Ba)) - 1.0f);
    }
  }
}

// All 6 smoothing ops (D,E,E,D,D,E) on a 32x128 tile, fully in LDS, plus the
// coarse histogram of the final values (hist storage aliases the idle buffer).
__global__ __launch_bounds__(256)
void fused_morph_k(const float* __restrict__ in, float* __restrict__ out,
                   unsigned* __restrict__ gh, unsigned* __restrict__ under,
                   unsigned* __restrict__ over){
  __shared__ float lds[2][LR*LCP];
  const int tilec = blockIdx.x & 15;       // 16 col tiles
  const int tiler = blockIdx.x >> 4;       // 64 row tiles
  const int r0 = tiler*TH, c0 = tilec*TW;

  // ---- load 44 rows x 36 aligned float4 (cols c0-8 .. c0+136), zero-padded ----
  for (int idx = threadIdx.x; idx < LR*36; idx += 256){
    int lr = idx / 36, g = idx % 36;
    int gr = r0 - 6 + lr, gc = c0 - 8 + 4*g;
    float4 v = make_float4(0.f,0.f,0.f,0.f);
    if ((unsigned)gr < (unsigned)HH && (unsigned)gc < (unsigned)WW)
      v = *reinterpret_cast<const float4*>(in + (size_t)gr*WW + gc);
    *reinterpret_cast<float4*>(&lds[0][lr*LCP + 4*g]) = v;
  }
  __syncthreads();

  const int t = threadIdx.x;
  const int g = t % 36, s = t / 36;        // strip s covers compute rows [6s+1, 6s+7)
  const bool active = (t < 252);
  const int lane = t & 63;
  const int gcBase = c0 - 8 + 4*g;
  const bool dilf[6] = {true,false,false,true,true,false};

  #pragma unroll 1
  for (int st = 0; st < 6; st++){
    const float* src = lds[st & 1];
    float*       dst = lds[(st & 1) ^ 1];
    if (active){
      const bool DIL = dilf[st];
      float4 vp, vc;  float pL,pR,cL,cR;
      loadrow(src, 6*s,     g, lane, vp, pL, pR);
      loadrow(src, 6*s + 1, g, lane, vc, cL, cR);
      #pragma unroll 1
      for (int k = 0; k < 6; k++){
        int lr = 6*s + 1 + k;
        float4 vn; float nL,nR;
        loadrow(src, lr + 1, g, lane, vn, nL, nR);
        float pr[6] = {pL, vp.x, vp.y, vp.z, vp.w, pR};
        float cr[6] = {cL, vc.x, vc.y, vc.z, vc.w, cR};
        float nr[6] = {nL, vn.x, vn.y, vn.z, vn.w, nR};
        float w[4];
        morph4(DIL, pr, cr, nr, w);
        int gr = r0 - 6 + lr;
        if ((unsigned)gr >= (unsigned)HH){
          w[0]=w[1]=w[2]=w[3]=0.f;
        } else {
          #pragma unroll
          for (int i = 0; i < 4; i++)
            if ((unsigned)(gcBase + i) >= (unsigned)WW) w[i] = 0.f;
        }
        *reinterpret_cast<float4*>(&dst[lr*LCP + 4*g]) = make_float4(w[0],w[1],w[2],w[3]);
        vp = vc; pL = cL; pR = cR;
        vc = vn; cL = nL; cR = nR;
      }
    }
    __syncthreads();
  }
  // final values live in lds[0]; lds[1] is free -> coarse histogram storage
  unsigned* lh = reinterpret_cast<unsigned*>(&lds[1][0]);
  for (int i = threadIdx.x; i < NBINS; i += 256) lh[i] = 0;
  __syncthreads();

  unsigned uc = 0, oc = 0;
  for (int idx = threadIdx.x; idx < TH*(TW/4); idx += 256){
    int row = idx >> 5, gg = idx & 31;
    float4 v = *reinterpret_cast<const float4*>(&lds[0][(row+6)*LCP + 8 + 4*gg]);
    *reinterpret_cast<float4*>(out + (size_t)(r0+row)*WW + c0 + 4*gg) = v;
    float vv[4] = {v.x, v.y, v.z, v.w};
    #pragma unroll
    for (int i = 0; i < 4; i++){
      unsigned key = keyf(vv[i]);
      unsigned hi = key >> 16;
      if (hi >= KEYLO && hi < KEYHI_) atomicAdd(&lh[hi - KEYLO], 1u);
      else if (hi < KEYLO)            uc++;
      else                            oc++;
    }
  }
  __syncthreads();
  for (int i = threadIdx.x; i < NBINS; i += 256){
    unsigned c = lh[i];
    if (c) atomicAdd(&gh[i], c);
  }
  if (uc) atomicAdd(under, uc);
  if (oc) atomicAdd(over, oc);
}

__global__ void scan_coarse_k(const unsigned* __restrict__ gh, const unsigned* __restrict__ under,
                              Scal* __restrict__ sc){
  __shared__ unsigned part[256];
  __shared__ unsigned excl[256];
  int t = threadIdx.x;
  unsigned loc = 0;
  #pragma unroll
  for (int i = 0; i < NBINS/256; i++) loc += gh[t*(NBINS/256) + i];
  part[t] = loc;
  __syncthreads();
  if (t == 0){
    unsigned run = under[0];
    for (int i = 0; i < 256; i++){ excl[i] = run; run += part[i]; }
  }
  __syncthreads();
  unsigned run = excl[t];
  const unsigned r0 = RANK0, r1 = RANK0 + 1;
  #pragma unroll
  for (int i = 0; i < NBINS/256; i++){
    unsigned idx = t*(NBINS/256) + i;
    unsigned cc = gh[idx];
    if (cc){
      if (r0 >= run && r0 - run < cc){ sc->keyhiA = KEYLO + idx; sc->rA = r0 - run; }
      if (r1 >= run && r1 - run < cc){ sc->keyhiB = KEYLO + idx; sc->rB = r1 - run; }
    }
    run += cc;
  }
}

// mid-byte histogram (bits 15..8) of keys whose hi16 matches keyhiA / keyhiB
__global__ __launch_bounds__(256)
void fine_mid_k(const float* __restrict__ x, const Scal* __restrict__ sc,
                unsigned* __restrict__ midA, unsigned* __restrict__ midB){
  __shared__ unsigned hA[256], hB[256];
  hA[threadIdx.x] = 0; hB[threadIdx.x] = 0;
  __syncthreads();
  unsigned ha = sc->keyhiA, hb = sc->keyhiB;
  bool dup = (ha == hb);
  const int nItems = NN/4;
  for (int it = blockIdx.x*blockDim.x + threadIdx.x; it < nItems; it += gridDim.x*blockDim.x){
    float4 v = reinterpret_cast<const float4*>(x)[it];
    float vv[4] = {v.x, v.y, v.z, v.w};
    #pragma unroll
    for (int t = 0; t < 4; t++){
      unsigned key = keyf(vv[t]);
      unsigned hi = key >> 16;
      if (hi == ha)      atomicAdd(&hA[(key >> 8) & 0xFFu], 1u);
      else if (hi == hb) atomicAdd(&hB[(key >> 8) & 0xFFu], 1u);
    }
  }
  __syncthreads();
  unsigned ca = hA[threadIdx.x];
  if (ca) atomicAdd(&midA[threadIdx.x], ca);
  if (!dup){
    unsigned cb = hB[threadIdx.x];
    if (cb) atomicAdd(&midB[threadIdx.x], cb);
  }
}

__global__ void scan_mid_k(const unsigned* __restrict__ midA, const unsigned* __restrict__ midB,
                           Scal* __restrict__ sc){
  __shared__ unsigned h[256], excl[256];
  int t = threadIdx.x;
  bool dup = (sc->keyhiA == sc->keyhiB);
  unsigned rA = sc->rA, rB = sc->rB;
  h[t] = midA[t];
  __syncthreads();
  if (t == 0){ unsigned run = 0; for (int i = 0; i < 256; i++){ excl[i] = run; run += h[i]; } }
  __syncthreads();
  if (rA >= excl[t] && rA - excl[t] < h[t]){ sc->midA_ = (unsigned)t; sc->rA2 = rA - excl[t]; }
  if (dup && rB >= excl[t] && rB - excl[t] < h[t]){ sc->midB_ = (unsigned)t; sc->rB2 = rB - excl[t]; }
  if (!dup){
    __syncthreads();
    h[t] = midB[t];
    __syncthreads();
    if (t == 0){ unsigned run = 0; for (int i = 0; i < 256; i++){ excl[i] = run; run += h[i]; } }
    __syncthreads();
    if (rB >= excl[t] && rB - excl[t] < h[t]){ sc->midB_ = (unsigned)t; sc->rB2 = rB - excl[t]; }
  }
}

// low-byte histogram of keys with hi16 AND mid byte matching
__global__ __launch_bounds__(256)
void fine_low_k(const float* __restrict__ x, const Scal* __restrict__ sc,
                unsigned* __restrict__ lowA, unsigned* __restrict__ lowB){
  __shared__ unsigned hA[256], hB[256];
  hA[threadIdx.x] = 0; hB[threadIdx.x] = 0;
  __syncthreads();
  unsigned ha = sc->keyhiA, hb = sc->keyhiB;
  unsigned ma = sc->midA_, mb = sc->midB_;
  bool dup = (ha == hb) && (ma == mb);
  const int nItems = NN/4;
  for (int it = blockIdx.x*blockDim.x + threadIdx.x; it < nItems; it += gridDim.x*blockDim.x){
    float4 v = reinterpret_cast<const float4*>(x)[it];
    float vv[4] = {v.x, v.y, v.z, v.w};
    #pragma unroll
    for (int t = 0; t < 4; t++){
      unsigned key = keyf(vv[t]);
      unsigned hi = key >> 16;
      unsigned m  = (key >> 8) & 0xFFu;
      if (hi == ha && m == ma)      atomicAdd(&hA[key & 0xFFu], 1u);
      else if (hi == hb && m == mb) atomicAdd(&hB[key & 0xFFu], 1u);
    }
  }
  __syncthreads();
  unsigned ca = hA[threadIdx.x];
  if (ca) atomicAdd(&lowA[threadIdx.x], ca);
  if (!dup){
    unsigned cb = hB[threadIdx.x];
    if (cb) atomicAdd(&lowB[threadIdx.x], cb);
  }
}

__global__ void scan_low_k(const unsigned* __restrict__ lowA, const unsigned* __restrict__ lowB,
                           Scal* __restrict__ sc){
  __shared__ unsigned h[256], excl[256];
  __shared__ unsigned kfound[2];
  int t = threadIdx.x;
  bool dup = (sc->keyhiA == sc->keyhiB) && (sc->midA_ == sc->midB_);
  unsigned rA2 = sc->rA2, rB2 = sc->rB2;
  h[t] = lowA[t];
  __syncthreads();
  if (t == 0){ unsigned run = 0; for (int i = 0; i < 256; i++){ excl[i] = run; run += h[i]; } }
  __syncthreads();
  if (rA2 >= excl[t] && rA2 - excl[t] < h[t]) kfound[0] = (unsigned)t;
  if (dup && rB2 >= excl[t] && rB2 - excl[t] < h[t]) kfound[1] = (unsigned)t;
  if (!dup){
    __syncthreads();
    h[t] = lowB[t];
    __syncthreads();
    if (t == 0){ unsigned run = 0; for (int i = 0; i < 256; i++){ excl[i] = run; run += h[i]; } }
    __syncthreads();
    if (rB2 >= excl[t] && rB2 - excl[t] < h[t]) kfound[1] = (unsigned)t;
  }
  __syncthreads();
  if (t == 0){
    unsigned ka = (sc->keyhiA << 16) | (sc->midA_ << 8) | kfound[0];
    unsigned kb = (sc->keyhiB << 16) | (sc->midB_ << 8) | kfound[1];
    double va = (double)keyinv(ka), vb = (double)keyinv(kb);
    const double FRAC = 0.4*(double)(NN-1) - (double)RANK0;   // np's interpolation gamma
    sc->thr = va + (vb - va) * FRAC;
  }
}

// load cols q-1..q+4 of `row` with zero padding (rows and cols)
__device__ __forceinline__ void load6(const float* __restrict__ p, int row, int q, float r[6]){
  if (row < 0 || row >= HH){
    r[0]=r[1]=r[2]=r[3]=r[4]=r[5]=0.f;
    return;
  }
  const float* rp = p + (size_t)row * WW;
  float4 cc = *reinterpret_cast<const float4*>(rp + q);
  r[0] = (q > 0) ? rp[q-1] : 0.f;
  r[1]=cc.x; r[2]=cc.y; r[3]=cc.z; r[4]=cc.w;
  r[5] = (q+4 < WW) ? rp[q+4] : 0.f;
}

// balloon step: aux = 1 + M9(x) computed inline; xb = (origin > thr) ? aux : x.
// Also f64 partial sums of origin, xb, origin*xb per block.
__global__ __launch_bounds__(256)
void balloon_k(const float* __restrict__ x, const float* __restrict__ orig,
               float* __restrict__ xb, const Scal* __restrict__ sc, double* __restrict__ part){
  double thr = sc->thr;
  double s0 = 0.0, s1 = 0.0, s2 = 0.0;   // So, Sx, Sox
  const int nItems = NN/4;
  for (int it = blockIdx.x*blockDim.x + threadIdx.x; it < nItems; it += gridDim.x*blockDim.x){
    int i = it >> 9;
    int q = (it & 511) << 2;
    float a[6], b[6], c[6];
    load6(x, i-1, q, a);
    load6(x, i,   q, b);
    load6(x, i+1, q, c);
    float4 og = *reinterpret_cast<const float4*>(orig + (size_t)i*WW + q);
    float ov[4] = {og.x, og.y, og.z, og.w};
    float r[4];
    #pragma unroll
    for (int t = 0; t < 4; t++){
      float M9 = mx3(mx3(a[t],a[t+1],a[t+2]), mx3(b[t],b[t+1],b[t+2]), mx3(c[t],c[t+1],c[t+2]));
      float aux = 1.0f + M9;
      float nx = ((double)ov[t] > thr) ? aux : b[t+1];
      r[t] = nx;
      s0 += (double)ov[t];
      s1 += (double)nx;
      s2 += (double)ov[t] * (double)nx;
    }
    *reinterpret_cast<float4*>(xb + (size_t)i*WW + q) = make_float4(r[0],r[1],r[2],r[3]);
  }
  for (int off = 32; off > 0; off >>= 1){
    s0 += __shfl_down(s0, off);
    s1 += __shfl_down(s1, off);
    s2 += __shfl_down(s2, off);
  }
  __shared__ double red[4][3];
  int lane = threadIdx.x & 63, wv = threadIdx.x >> 6;
  if (lane == 0){ red[wv][0] = s0; red[wv][1] = s1; red[wv][2] = s2; }
  __syncthreads();
  if (threadIdx.x == 0){
    part[blockIdx.x*3+0] = red[0][0]+red[1][0]+red[2][0]+red[3][0];
    part[blockIdx.x*3+1] = red[0][1]+red[1][1]+red[2][1]+red[3][1];
    part[blockIdx.x*3+2] = red[0][2]+red[1][2]+red[2][2]+red[3][2];
  }
}

__global__ void c0c1_k(const double* __restrict__ part, Scal* __restrict__ sc){
  int t = threadIdx.x;
  double s0 = 0, s1 = 0, s2 = 0;
  for (int b = t; b < NPART; b += 256){
    s0 += part[b*3+0]; s1 += part[b*3+1]; s2 += part[b*3+2];
  }
  for (int off = 32; off > 0; off >>= 1){
    s0 += __shfl_down(s0, off);
    s1 += __shfl_down(s1, off);
    s2 += __shfl_down(s2, off);
  }
  __shared__ double red[4][3];
  int lane = t & 63, wv = t >> 6;
  if (lane == 0){ red[wv][0] = s0; red[wv][1] = s1; red[wv][2] = s2; }
  __syncthreads();
  if (t == 0){
    double So = red[0][0]+red[1][0]+red[2][0]+red[3][0];
    double Sx = red[0][1]+red[1][1]+red[2][1]+red[3][1];
    double Sox= red[0][2]+red[1][2]+red[2][2]+red[3][2];
    sc->c0 = (So - Sox) / ((double)NN - Sx + 1e-8);
    sc->c1 = Sox / (Sx + 1e-8);
  }
}

__global__ __launch_bounds__(256)
void final_k(const float* __restrict__ orig, const float* __restrict__ xb,
             const Scal* __restrict__ sc, float* __restrict__ out){
  double c0 = sc->c0, c1 = sc->c1;
  const int nItems = NN/4;
  for (int it = blockIdx.x*blockDim.x + threadIdx.x; it < nItems; it += gridDim.x*blockDim.x){
    float4 og = reinterpret_cast<const float4*>(orig)[it];
    float4 xv = reinterpret_cast<const float4*>(xb)[it];
    float ov[4] = {og.x, og.y, og.z, og.w};
    float xx[4] = {xv.x, xv.y, xv.z, xv.w};
    float r[4];
    #pragma unroll
    for (int t = 0; t < 4; t++){
      double o = (double)ov[t];
      double d1 = o - c1, d0 = o - c0;
      double cv = d1*d1 - d0*d0;
      r[t] = (cv < 0.0) ? 1.0f : ((cv > 0.0) ? 0.0f : xx[t]);
    }
    reinterpret_cast<float4*>(out)[it] = make_float4(r[0],r[1],r[2],r[3]);
  }
}

extern "C" void kernel_launch(void* const* d_in, const int* in_sizes, int n_in,
                              void* d_out, int out_size, void* d_ws, size_t ws_size,
                              hipStream_t stream) {
  const float* input  = (const float*)d_in[0];
  const float* origin = (const float*)d_in[1];
  float* out = (float*)d_out;

  char* ws = (char*)d_ws;
  float*    bufA   = (float*)ws;
  unsigned* coarse = (unsigned*)(ws + OFF_COARSE);
  unsigned* under  = (unsigned*)(ws + OFF_UNDER);
  unsigned* over   = (unsigned*)(ws + OFF_OVER);
  Scal*     scal   = (Scal*)(ws + OFF_SCAL);
  double*   part   = (double*)(ws + OFF_PART);
  unsigned* midA   = (unsigned*)(ws + OFF_MIDA);
  unsigned* midB   = (unsigned*)(ws + OFF_MIDB);
  unsigned* lowA   = (unsigned*)(ws + OFF_LOWA);
  unsigned* lowB   = (unsigned*)(ws + OFF_LOWB);

  hipMemsetAsync(ws + OFF_CTL, 0, CTL_BYTES, stream);

  // all 6 smoothing ops + coarse hist in one tiled kernel; x_final -> d_out
  fused_morph_k<<<(HH/TH)*(WW/TW), 256, 0, stream>>>(input, out, coarse, under, over);

  scan_coarse_k<<<1, 256, 0, stream>>>(coarse, under, scal);
  fine_mid_k<<<1024, 256, 0, stream>>>(out, scal, midA, midB);
  scan_mid_k<<<1, 256, 0, stream>>>(midA, midB, scal);
  fine_low_k<<<1024, 256, 0, stream>>>(out, scal, lowA, lowB);
  scan_low_k<<<1, 256, 0, stream>>>(lowA, lowB, scal);

  balloon_k<<<NPART, 256, 0, stream>>>(out, origin, bufA, scal, part);   // xb in bufA
  c0c1_k<<<1, 256, 0, stream>>>(part, scal);
  final_k<<<2048, 256, 0, stream>>>(origin, bufA, scal, out);
}